// Round 9
// baseline (330.766 us; speedup 1.0000x reference)
//
#include <hip/hip_runtime.h>
#include <hip/hip_bf16.h>

typedef _Float16 half8  __attribute__((ext_vector_type(8)));
typedef _Float16 half4v __attribute__((ext_vector_type(4)));
typedef float    f32x4  __attribute__((ext_vector_type(4)));

#define N_NODES 100000
#define N_EDGES 3200000
#define SH_STRIDE 100096   // fallback shadow stride (floats)
#define NBUCK 782          // 128 nodes per bucket == one sage tile
#define CAP   5120         // pairs/bucket: mean 4092 + 16 sigma
#define CHUNK 12288        // edges per bin block (1024 thr x 3 x int4)
#define NBIN  261          // ceil(N_EDGES/CHUNK)
#define NPK   16           // pack blocks appended to bin grid

// ---------------------------------------------------------------------------
// Merged bin + pack kernel, 1024-thread blocks.
// bin blocks [0,NBIN): block-local counting sort for COALESCED output:
//   phase1: LDS histogram by dst>>7 (edges held in registers)
//   reserve: one global atomic per nonzero bucket (~204K total)
//   scan:    Hillis-Steele prefix over 782 buckets -> LDS group bases
//   phase2:  place {record, gslot} into LDS grouped by bucket
//   phase3:  linear LDS read -> runs of consecutive gslot -> coalesced stores
//   record = (fp32_bits & 0xFFFFFF00) | (dst & 127)   (rel err <= 2^-16)
// pack blocks [NBIN,NBIN+NPK): weights fp32->fp16 + park[] table:
//   park[l*512+j]=we_l[j]; park[l*512+256+j]=bias_l[j];
//   park[3584+j]=wr3[j]; park[3840]=br3[0]
// ---------------------------------------------------------------------------
__global__ __launch_bounds__(1024) void binpack(
    const float* __restrict__ ef, const int* __restrict__ dst,
    const float* __restrict__ W1,  const float* __restrict__ Wm1,
    const float* __restrict__ Wm2, const float* __restrict__ Wm3,
    const float* __restrict__ Wm4, const float* __restrict__ Wr1,
    const float* __restrict__ Wr2,
    const float* __restrict__ b1,  const float* __restrict__ bm1,
    const float* __restrict__ bm2, const float* __restrict__ bm3,
    const float* __restrict__ bm4, const float* __restrict__ br1,
    const float* __restrict__ br2, const float* __restrict__ wr3,
    const float* __restrict__ br3,
    int* __restrict__ cursor, unsigned* __restrict__ pairs,
    _Float16* __restrict__ Wp, float* __restrict__ park, int do_bin) {

    if (do_bin && blockIdx.x < NBIN) {
        __shared__ int      hist[NBUCK];
        __shared__ int      base[NBUCK];   // absolute global base per bucket
        __shared__ int      scan[1024];    // prefix-sum workspace
        __shared__ int      lbase[NBUCK];  // LDS group base per bucket
        __shared__ unsigned lrec[CHUNK];   // grouped records
        __shared__ int      lslot[CHUNK];  // grouped global slots (-1 = drop)
        const int start = blockIdx.x * CHUNK;
        const int tid   = threadIdx.x;
        for (int b = tid; b < NBUCK; b += 1024) hist[b] = 0;
        __syncthreads();

        int4   dreg[3];
        float4 freg[3];
        #pragma unroll
        for (int it = 0; it < 3; ++it) {
            const int i = start + (it * 1024 + tid) * 4;
            if (i < N_EDGES) {
                dreg[it] = *(const int4*)&dst[i];
                freg[it] = *(const float4*)&ef[i];
                atomicAdd(&hist[dreg[it].x >> 7], 1);
                atomicAdd(&hist[dreg[it].y >> 7], 1);
                atomicAdd(&hist[dreg[it].z >> 7], 1);
                atomicAdd(&hist[dreg[it].w >> 7], 1);
            }
        }
        __syncthreads();
        // reserve global space; seed scan with counts
        if (tid < NBUCK) {
            const int c = hist[tid];
            base[tid] = tid * CAP + ((c > 0) ? atomicAdd(&cursor[tid], c) : 0);
            scan[tid] = c;
        } else {
            scan[tid] = 0;
        }
        __syncthreads();
        // Hillis-Steele inclusive scan over 1024 slots
        #pragma unroll
        for (int ofs = 1; ofs < 1024; ofs <<= 1) {
            const int v = (tid >= ofs) ? scan[tid - ofs] : 0;
            __syncthreads();
            scan[tid] += v;
            __syncthreads();
        }
        if (tid < NBUCK) {
            lbase[tid] = scan[tid] - hist[tid];   // exclusive
            hist[tid]  = 0;                        // reuse as running rank
        }
        __syncthreads();
        // phase2: place into LDS grouped by bucket
        #pragma unroll
        for (int it = 0; it < 3; ++it) {
            const int i = start + (it * 1024 + tid) * 4;
            if (i < N_EDGES) {
                const int4   d = dreg[it];
                const float4 f = freg[it];
                {   const int bk = d.x >> 7; const int r = atomicAdd(&hist[bk], 1);
                    const int s = lbase[bk] + r; const int g = base[bk] + r;
                    lrec[s]  = (__float_as_uint(f.x) & 0xFFFFFF00u) | (unsigned)(d.x & 127);
                    lslot[s] = (g < (bk + 1) * CAP) ? g : -1; }
                {   const int bk = d.y >> 7; const int r = atomicAdd(&hist[bk], 1);
                    const int s = lbase[bk] + r; const int g = base[bk] + r;
                    lrec[s]  = (__float_as_uint(f.y) & 0xFFFFFF00u) | (unsigned)(d.y & 127);
                    lslot[s] = (g < (bk + 1) * CAP) ? g : -1; }
                {   const int bk = d.z >> 7; const int r = atomicAdd(&hist[bk], 1);
                    const int s = lbase[bk] + r; const int g = base[bk] + r;
                    lrec[s]  = (__float_as_uint(f.z) & 0xFFFFFF00u) | (unsigned)(d.z & 127);
                    lslot[s] = (g < (bk + 1) * CAP) ? g : -1; }
                {   const int bk = d.w >> 7; const int r = atomicAdd(&hist[bk], 1);
                    const int s = lbase[bk] + r; const int g = base[bk] + r;
                    lrec[s]  = (__float_as_uint(f.w) & 0xFFFFFF00u) | (unsigned)(d.w & 127);
                    lslot[s] = (g < (bk + 1) * CAP) ? g : -1; }
            }
        }
        __syncthreads();
        // phase3: coalesced run writes (consecutive s within a bucket run
        // -> consecutive global slots)
        const int total = min(CHUNK, N_EDGES - start);
        for (int s = tid; s < total; s += 1024) {
            const int g = lslot[s];
            if (g >= 0) pairs[g] = lrec[s];
        }
    } else {
        const float* srcs[7] = {W1, Wm1, Wm2, Wm3, Wm4, Wr1, Wr2};
        const float* bias[7] = {b1, bm1, bm2, bm3, bm4, br1, br2};
        const int pb  = do_bin ? ((int)blockIdx.x - NBIN) : (int)blockIdx.x;
        const int gid = pb * 1024 + threadIdx.x;
        const int gsz = NPK * 1024;
        for (int i = gid; i < 425984; i += gsz) {
            int job, row, k, stride;
            if (i < 32768) { job = 0; row = i >> 7; k = i & 127; stride = 129; }
            else {
                int t = i - 32768; job = 1 + (t >> 16); int w = t & 65535;
                row = w >> 8; k = w & 255; stride = (job == 6) ? 256 : 257;
            }
            Wp[i] = (_Float16)srcs[job][row * stride + k];
        }
        for (int i = gid; i < 1536; i += gsz) {
            const int job = i >> 8, row = i & 255;
            const int stride = (job == 0) ? 129 : 257;
            const int kin    = (job == 0) ? 128 : 256;
            park[job * 512 + row] = srcs[job][row * stride + kin];
        }
        for (int i = gid; i < 256; i += gsz) park[6 * 512 + i] = 0.f;
        for (int i = gid; i < 1792; i += gsz)
            park[(i >> 8) * 512 + 256 + (i & 255)] = bias[i >> 8][i & 255];
        for (int i = gid; i < 256; i += gsz) park[3584 + i] = wr3[i];
        if (gid == 0) park[3840] = br3[0];
    }
}

// fallback: device-scope split-4 scatter (known-good)
__global__ void scatter4(const float4* __restrict__ ef4,
                         const int4* __restrict__ dst4,
                         float* __restrict__ e) {
    const int n4 = N_EDGES / 4;
    for (int i = blockIdx.x * blockDim.x + threadIdx.x; i < n4;
         i += gridDim.x * blockDim.x) {
        const float4 f = ef4[i];
        const int4   d = dst4[i];
        atomicAdd(&e[d.x], f.x);
        atomicAdd(&e[SH_STRIDE + d.y], f.y);
        atomicAdd(&e[2 * SH_STRIDE + d.z], f.z);
        atomicAdd(&e[3 * SH_STRIDE + d.w], f.w);
    }
}

// ---------------------------------------------------------------------------
// One layer over a 128-node tile (proven shape). Wave owns 64 output cols x
// 128 nodes: jt4 x mt8. a-frag = W rows from global/L2, prefetched one
// k-step ahead; b-frag = H rows via ds_read_b128. Epilogue constants (we,
// bias) preloaded to REGISTERS from park. Two barriers per layer.
// D: col=lane&15 -> node, row=quad*4+r -> 4 consecutive output features ->
// packed 8B LDS stores.
// ---------------------------------------------------------------------------
template<int K>
__device__ __forceinline__ void layer_mm(const _Float16* __restrict__ Wl,
                                         _Float16 (* __restrict__ Hs)[264],
                                         const float* __restrict__ es,
                                         const float* __restrict__ parkl,
                                         int wave, int m_, int quad) {
    f32x4 acc[4][8];
    #pragma unroll
    for (int jt = 0; jt < 4; ++jt)
        #pragma unroll
        for (int mt = 0; mt < 8; ++mt)
            acc[jt][mt] = (f32x4){0.f, 0.f, 0.f, 0.f};

    const int jb0 = wave * 64 + quad * 4;
    float4 w4[4], bb[4];
    #pragma unroll
    for (int jt = 0; jt < 4; ++jt) {
        w4[jt] = *(const float4*)&parkl[jt * 16 + jb0];
        bb[jt] = *(const float4*)&parkl[256 + jt * 16 + jb0];
    }

    const _Float16* __restrict__ wp = Wl + (size_t)(wave * 64 + m_) * K + quad * 8;

    half8 a[4];
    #pragma unroll
    for (int jt = 0; jt < 4; ++jt)
        a[jt] = *(const half8*)(wp + jt * 16 * K);

    #pragma unroll
    for (int kk = 0; kk < K; kk += 32) {
        half8 a2[4];
        if (kk + 32 < K) {
            #pragma unroll
            for (int jt = 0; jt < 4; ++jt)
                a2[jt] = *(const half8*)(wp + jt * 16 * K + kk + 32);
        }
        half8 b[8];
        #pragma unroll
        for (int mt = 0; mt < 8; ++mt)
            b[mt] = *(const half8*)&Hs[mt * 16 + m_][kk + quad * 8];
        #pragma unroll
        for (int jt = 0; jt < 4; ++jt)
            #pragma unroll
            for (int mt = 0; mt < 8; ++mt)
                acc[jt][mt] = __builtin_amdgcn_mfma_f32_16x16x32_f16(
                    a[jt], b[mt], acc[jt][mt], 0, 0, 0);
        if (kk + 32 < K) {
            #pragma unroll
            for (int jt = 0; jt < 4; ++jt) a[jt] = a2[jt];
        }
    }
    __syncthreads();   // all waves done reading Hs

    #pragma unroll
    for (int jt = 0; jt < 4; ++jt) {
        const int jbase = jb0 + jt * 16;
        #pragma unroll
        for (int mt = 0; mt < 8; ++mt) {
            const int node = mt * 16 + m_;
            const float ev = es[node];
            half4v h;
            h[0] = (_Float16)fmaxf(acc[jt][mt][0] + ev * w4[jt].x + bb[jt].x, 0.f);
            h[1] = (_Float16)fmaxf(acc[jt][mt][1] + ev * w4[jt].y + bb[jt].y, 0.f);
            h[2] = (_Float16)fmaxf(acc[jt][mt][2] + ev * w4[jt].z + bb[jt].z, 0.f);
            h[3] = (_Float16)fmaxf(acc[jt][mt][3] + ev * w4[jt].w + bb[jt].w, 0.f);
            *(half4v*)&Hs[node][jbase] = h;
        }
    }
    __syncthreads();   // Hs writes visible before next layer
}

// ---------------------------------------------------------------------------
// NOTE: no min-waves bound — (256,2) made the allocator cap at 128 VGPR and
// spill 9.4 MB/launch to scratch (R8 counters). LDS (70 KB) already pins
// occupancy at 2 blocks/CU.
__global__ __launch_bounds__(256) void sage_fused(
    const float* __restrict__ node_feat,
    const int* __restrict__ cursor, const unsigned* __restrict__ pairs,
    const float* __restrict__ esh, int nsh,
    const _Float16* __restrict__ Wpack, const float* __restrict__ park,
    float* __restrict__ out) {

    __shared__ _Float16 Hs[128][264];   // +8-half pad
    __shared__ float es[128];
    __shared__ float wf[256];
    __shared__ float red[2][128];

    const int tid  = threadIdx.x;
    const int wave = tid >> 6;
    const int lane = tid & 63;
    const int m_   = lane & 15;
    const int quad = lane >> 4;
    const int node0 = blockIdx.x * 128;

    if (tid < 128) es[tid] = 0.f;
    __syncthreads();

    // ---- stage node_feat tile (fp32 -> fp16) ----
    for (int idx = tid; idx < 128 * 16; idx += 256) {
        const int row = idx >> 4, g = idx & 15;
        int node = node0 + row; if (node >= N_NODES) node = N_NODES - 1;
        const float4* src = (const float4*)(node_feat + (size_t)node * 128 + g * 8);
        const float4 v0 = src[0], v1 = src[1];
        half8 h;
        h[0] = (_Float16)v0.x; h[1] = (_Float16)v0.y;
        h[2] = (_Float16)v0.z; h[3] = (_Float16)v0.w;
        h[4] = (_Float16)v1.x; h[5] = (_Float16)v1.y;
        h[6] = (_Float16)v1.z; h[7] = (_Float16)v1.w;
        *(half8*)&Hs[row][g * 8] = h;
    }
    // ---- edge aggregate for this 128-node tile (1:1 bucket) ----
    if (nsh == 0) {
        const int cnt = min(cursor[blockIdx.x], CAP);
        const unsigned* __restrict__ pp = pairs + (size_t)blockIdx.x * CAP;
        for (int i = tid; i < cnt; i += 256) {
            const unsigned p = pp[i];
            atomicAdd(&es[p & 127u], __uint_as_float(p & 0xFFFFFF00u));
        }
    } else if (tid < 128) {
        int node = node0 + tid; if (node >= N_NODES) node = N_NODES - 1;
        float s = 0.f;
        for (int sh = 0; sh < nsh; ++sh) s += esh[(size_t)sh * SH_STRIDE + node];
        es[tid] = s;
    }
    __syncthreads();

    // layer 0: K=128; layers 1..6: K=256 (in-place Hs, 2 barriers each)
    layer_mm<128>(Wpack, Hs, es, park, wave, m_, quad);
    for (int l = 1; l < 7; ++l)
        layer_mm<256>(Wpack + 32768 + (l - 1) * 65536, Hs, es, park + l * 512,
                      wave, m_, quad);

    // ---- final 256 -> 1 dot (fp32) ----
    wf[tid] = park[3584 + tid];
    __syncthreads();
    {
        const int row = tid & 127, seg = tid >> 7;
        const _Float16* hp = &Hs[row][seg * 128];
        const float* wpt = &wf[seg * 128];
        float s = 0.f;
        #pragma unroll 8
        for (int k = 0; k < 128; ++k) s += (float)hp[k] * wpt[k];
        red[seg][row] = s;
    }
    __syncthreads();
    if (tid < 128) {
        const int node = node0 + tid;
        if (node < N_NODES)
            out[node] = red[0][tid] + red[1][tid] + park[3840];
    }
}

// ---------------------------------------------------------------------------
extern "C" void kernel_launch(void* const* d_in, const int* in_sizes, int n_in,
                              void* d_out, int out_size, void* d_ws,
                              size_t ws_size, hipStream_t stream) {
    const float* node_feat = (const float*)d_in[0];
    const float* edge_feat = (const float*)d_in[1];
    const int*   edge_dst  = (const int*)d_in[2];
    const float* W1  = (const float*)d_in[3];  const float* b1  = (const float*)d_in[4];
    const float* Wm1 = (const float*)d_in[5];  const float* bm1 = (const float*)d_in[6];
    const float* Wm2 = (const float*)d_in[7];  const float* bm2 = (const float*)d_in[8];
    const float* Wm3 = (const float*)d_in[9];  const float* bm3 = (const float*)d_in[10];
    const float* Wm4 = (const float*)d_in[11]; const float* bm4 = (const float*)d_in[12];
    const float* Wr1 = (const float*)d_in[13]; const float* br1 = (const float*)d_in[14];
    const float* Wr2 = (const float*)d_in[15]; const float* br2 = (const float*)d_in[16];
    const float* Wr3 = (const float*)d_in[17]; const float* br3 = (const float*)d_in[18];
    float* out = (float*)d_out;

    // ws layout: cursor | Wp | park | pairs (or fallback shadows)
    char* ws = (char*)d_ws;
    int*      cursor = (int*)ws;                           // 4096 B reserved
    _Float16* Wp     = (_Float16*)(ws + 4096);             // 851968 B
    float*    park   = (float*)(ws + 856064);              // 16384 B
    unsigned* pairs  = (unsigned*)(ws + 872448);           // NBUCK*CAP*4 B
    float*    esh    = (float*)(ws + 872448);              // fallback shadows

    const size_t need_bins = 872448 + (size_t)NBUCK * CAP * 4;   // ~16.9 MB
    const bool use_bins = (ws_size >= need_bins);

    const int nblk = (N_NODES + 127) / 128;   // 782

    if (use_bins) {
        hipMemsetAsync(cursor, 0, NBUCK * sizeof(int), stream);
        binpack<<<NBIN + NPK, 1024, 0, stream>>>(
            edge_feat, edge_dst, W1, Wm1, Wm2, Wm3, Wm4, Wr1, Wr2,
            b1, bm1, bm2, bm3, bm4, br1, br2, Wr3, br3,
            cursor, pairs, Wp, park, 1);
        sage_fused<<<nblk, 256, 0, stream>>>(node_feat, cursor, pairs,
                                             nullptr, 0, Wp, park, out);
    } else {
        binpack<<<NPK, 1024, 0, stream>>>(
            edge_feat, edge_dst, W1, Wm1, Wm2, Wm3, Wm4, Wr1, Wr2,
            b1, bm1, bm2, bm3, bm4, br1, br2, Wr3, br3,
            cursor, pairs, Wp, park, 0);
        hipMemsetAsync(esh, 0, (size_t)4 * SH_STRIDE * 4, stream);
        scatter4<<<3125, 256, 0, stream>>>((const float4*)edge_feat,
                                           (const int4*)edge_dst, esh);
        sage_fused<<<nblk, 256, 0, stream>>>(node_feat, nullptr, nullptr,
                                             esh, 4, Wp, park, out);
    }
}

// Round 10
// 316.280 us; speedup vs baseline: 1.0458x; 1.0458x over previous
//
#include <hip/hip_runtime.h>
#include <hip/hip_bf16.h>

typedef _Float16 half8  __attribute__((ext_vector_type(8)));
typedef _Float16 half4v __attribute__((ext_vector_type(4)));
typedef float    f32x4  __attribute__((ext_vector_type(4)));

#define N_NODES 100000
#define N_EDGES 3200000
#define SH_STRIDE 100096   // fallback shadow stride (floats)
#define NBUCK 782          // 128 nodes per bucket == one sage tile
#define CAP   5120         // records/bucket: mean 4092 + 16 sigma
#define CHUNK 16384        // edges per hist/place block (1024 thr x 4 x int4)
#define NBIN  196          // ceil(N_EDGES/CHUNK)
#define NPK   16           // pack blocks appended to hist grid

// ---------------------------------------------------------------------------
// Phase A: per-block LDS histogram by dst>>7 -> coalesced counts[block][bucket]
// (NO global atomics). Pack blocks [NBIN, NBIN+NPK) convert weights fp32->fp16
// and build park[]: park[l*512+j]=we_l[j]; park[l*512+256+j]=bias_l[j];
// park[3584+j]=wr3[j]; park[3840]=br3[0].
// ---------------------------------------------------------------------------
__global__ __launch_bounds__(1024) void hist_pack(
    const int* __restrict__ dst,
    const float* __restrict__ W1,  const float* __restrict__ Wm1,
    const float* __restrict__ Wm2, const float* __restrict__ Wm3,
    const float* __restrict__ Wm4, const float* __restrict__ Wr1,
    const float* __restrict__ Wr2,
    const float* __restrict__ b1,  const float* __restrict__ bm1,
    const float* __restrict__ bm2, const float* __restrict__ bm3,
    const float* __restrict__ bm4, const float* __restrict__ br1,
    const float* __restrict__ br2, const float* __restrict__ wr3,
    const float* __restrict__ br3,
    int* __restrict__ counts, _Float16* __restrict__ Wp,
    float* __restrict__ park, int do_bin) {

    if (do_bin && blockIdx.x < NBIN) {
        __shared__ int hist[NBUCK];
        const int tid   = threadIdx.x;
        const int start = blockIdx.x * CHUNK;
        for (int b = tid; b < NBUCK; b += 1024) hist[b] = 0;
        __syncthreads();
        #pragma unroll
        for (int it = 0; it < 4; ++it) {
            const int i = start + (it * 1024 + tid) * 4;
            if (i < N_EDGES) {
                const int4 d = *(const int4*)&dst[i];
                atomicAdd(&hist[d.x >> 7], 1);
                atomicAdd(&hist[d.y >> 7], 1);
                atomicAdd(&hist[d.z >> 7], 1);
                atomicAdd(&hist[d.w >> 7], 1);
            }
        }
        __syncthreads();
        int* __restrict__ row = counts + (size_t)blockIdx.x * NBUCK;
        for (int b = tid; b < NBUCK; b += 1024) row[b] = hist[b];
    } else {
        const float* srcs[7] = {W1, Wm1, Wm2, Wm3, Wm4, Wr1, Wr2};
        const float* bias[7] = {b1, bm1, bm2, bm3, bm4, br1, br2};
        const int pb  = do_bin ? ((int)blockIdx.x - NBIN) : (int)blockIdx.x;
        const int gid = pb * 1024 + threadIdx.x;
        const int gsz = NPK * 1024;
        for (int i = gid; i < 425984; i += gsz) {
            int job, row, k, stride;
            if (i < 32768) { job = 0; row = i >> 7; k = i & 127; stride = 129; }
            else {
                int t = i - 32768; job = 1 + (t >> 16); int w = t & 65535;
                row = w >> 8; k = w & 255; stride = (job == 6) ? 256 : 257;
            }
            Wp[i] = (_Float16)srcs[job][row * stride + k];
        }
        for (int i = gid; i < 1536; i += gsz) {
            const int job = i >> 8, row = i & 255;
            const int stride = (job == 0) ? 129 : 257;
            const int kin    = (job == 0) ? 128 : 256;
            park[job * 512 + row] = srcs[job][row * stride + kin];
        }
        for (int i = gid; i < 256; i += gsz) park[6 * 512 + i] = 0.f;
        for (int i = gid; i < 1792; i += gsz)
            park[(i >> 8) * 512 + 256 + (i & 255)] = bias[i >> 8][i & 255];
        for (int i = gid; i < 256; i += gsz) park[3584 + i] = wr3[i];
        if (gid == 0) park[3840] = br3[0];
    }
}

// ---------------------------------------------------------------------------
// Phase B: one block. Thread t scans bucket t across all NBIN blocks
// (in-place exclusive prefix; reads/writes coalesced across lanes each
// iteration); also emits cnt[t] = total records in bucket t.
// ---------------------------------------------------------------------------
__global__ __launch_bounds__(1024) void scan_k(int* __restrict__ counts,
                                               int* __restrict__ cnt) {
    const int t = threadIdx.x;
    if (t < NBUCK) {
        int run = 0;
        #pragma unroll 4
        for (int j = 0; j < NBIN; ++j) {
            const int c = counts[(size_t)j * NBUCK + t];
            counts[(size_t)j * NBUCK + t] = run;
            run += c;
        }
        cnt[t] = run;
    }
}

// ---------------------------------------------------------------------------
// Phase C: place records. Per block: load its per-bucket bases (precomputed,
// deterministic -> no global atomics), LDS-rank within block, direct 4B
// scattered stores.  record = (fp32_bits & 0xFFFFFF00) | (dst & 127).
// ---------------------------------------------------------------------------
__global__ __launch_bounds__(1024) void place_k(
    const float* __restrict__ ef, const int* __restrict__ dst,
    const int* __restrict__ counts, unsigned* __restrict__ pairs) {
    __shared__ int basel[NBUCK];
    __shared__ int hist[NBUCK];
    const int tid   = threadIdx.x;
    const int start = blockIdx.x * CHUNK;
    const int* __restrict__ row = counts + (size_t)blockIdx.x * NBUCK;
    for (int b = tid; b < NBUCK; b += 1024) { basel[b] = row[b]; hist[b] = 0; }
    __syncthreads();
    #pragma unroll
    for (int it = 0; it < 4; ++it) {
        const int i = start + (it * 1024 + tid) * 4;
        if (i < N_EDGES) {
            const int4   d = *(const int4*)&dst[i];
            const float4 f = *(const float4*)&ef[i];
            {   const int bk = d.x >> 7; const int s = basel[bk] + atomicAdd(&hist[bk], 1);
                if (s < CAP) pairs[(size_t)bk * CAP + s] =
                    (__float_as_uint(f.x) & 0xFFFFFF00u) | (unsigned)(d.x & 127); }
            {   const int bk = d.y >> 7; const int s = basel[bk] + atomicAdd(&hist[bk], 1);
                if (s < CAP) pairs[(size_t)bk * CAP + s] =
                    (__float_as_uint(f.y) & 0xFFFFFF00u) | (unsigned)(d.y & 127); }
            {   const int bk = d.z >> 7; const int s = basel[bk] + atomicAdd(&hist[bk], 1);
                if (s < CAP) pairs[(size_t)bk * CAP + s] =
                    (__float_as_uint(f.z) & 0xFFFFFF00u) | (unsigned)(d.z & 127); }
            {   const int bk = d.w >> 7; const int s = basel[bk] + atomicAdd(&hist[bk], 1);
                if (s < CAP) pairs[(size_t)bk * CAP + s] =
                    (__float_as_uint(f.w) & 0xFFFFFF00u) | (unsigned)(d.w & 127); }
        }
    }
}

// fallback: device-scope split-4 scatter (known-good)
__global__ void scatter4(const float4* __restrict__ ef4,
                         const int4* __restrict__ dst4,
                         float* __restrict__ e) {
    const int n4 = N_EDGES / 4;
    for (int i = blockIdx.x * blockDim.x + threadIdx.x; i < n4;
         i += gridDim.x * blockDim.x) {
        const float4 f = ef4[i];
        const int4   d = dst4[i];
        atomicAdd(&e[d.x], f.x);
        atomicAdd(&e[SH_STRIDE + d.y], f.y);
        atomicAdd(&e[2 * SH_STRIDE + d.z], f.z);
        atomicAdd(&e[3 * SH_STRIDE + d.w], f.w);
    }
}

// ---------------------------------------------------------------------------
// One layer over a 128-node tile (R8-proven config). Wave owns 64 output cols
// x 128 nodes: jt4 x mt8. a-frag = W rows from global/L2, prefetched one
// k-step ahead; b-frag = H rows via ds_read_b128. Epilogue constants from
// park in registers. Two barriers per layer.
// ---------------------------------------------------------------------------
template<int K>
__device__ __forceinline__ void layer_mm(const _Float16* __restrict__ Wl,
                                         _Float16 (* __restrict__ Hs)[264],
                                         const float* __restrict__ es,
                                         const float* __restrict__ parkl,
                                         int wave, int m_, int quad) {
    f32x4 acc[4][8];
    #pragma unroll
    for (int jt = 0; jt < 4; ++jt)
        #pragma unroll
        for (int mt = 0; mt < 8; ++mt)
            acc[jt][mt] = (f32x4){0.f, 0.f, 0.f, 0.f};

    const int jb0 = wave * 64 + quad * 4;
    float4 w4[4], bb[4];
    #pragma unroll
    for (int jt = 0; jt < 4; ++jt) {
        w4[jt] = *(const float4*)&parkl[jt * 16 + jb0];
        bb[jt] = *(const float4*)&parkl[256 + jt * 16 + jb0];
    }

    const _Float16* __restrict__ wp = Wl + (size_t)(wave * 64 + m_) * K + quad * 8;

    half8 a[4];
    #pragma unroll
    for (int jt = 0; jt < 4; ++jt)
        a[jt] = *(const half8*)(wp + jt * 16 * K);

    #pragma unroll
    for (int kk = 0; kk < K; kk += 32) {
        half8 a2[4];
        if (kk + 32 < K) {
            #pragma unroll
            for (int jt = 0; jt < 4; ++jt)
                a2[jt] = *(const half8*)(wp + jt * 16 * K + kk + 32);
        }
        half8 b[8];
        #pragma unroll
        for (int mt = 0; mt < 8; ++mt)
            b[mt] = *(const half8*)&Hs[mt * 16 + m_][kk + quad * 8];
        #pragma unroll
        for (int jt = 0; jt < 4; ++jt)
            #pragma unroll
            for (int mt = 0; mt < 8; ++mt)
                acc[jt][mt] = __builtin_amdgcn_mfma_f32_16x16x32_f16(
                    a[jt], b[mt], acc[jt][mt], 0, 0, 0);
        if (kk + 32 < K) {
            #pragma unroll
            for (int jt = 0; jt < 4; ++jt) a[jt] = a2[jt];
        }
    }
    __syncthreads();   // all waves done reading Hs

    #pragma unroll
    for (int jt = 0; jt < 4; ++jt) {
        const int jbase = jb0 + jt * 16;
        #pragma unroll
        for (int mt = 0; mt < 8; ++mt) {
            const int node = mt * 16 + m_;
            const float ev = es[node];
            half4v h;
            h[0] = (_Float16)fmaxf(acc[jt][mt][0] + ev * w4[jt].x + bb[jt].x, 0.f);
            h[1] = (_Float16)fmaxf(acc[jt][mt][1] + ev * w4[jt].y + bb[jt].y, 0.f);
            h[2] = (_Float16)fmaxf(acc[jt][mt][2] + ev * w4[jt].z + bb[jt].z, 0.f);
            h[3] = (_Float16)fmaxf(acc[jt][mt][3] + ev * w4[jt].w + bb[jt].w, 0.f);
            *(half4v*)&Hs[node][jbase] = h;
        }
    }
    __syncthreads();   // Hs writes visible before next layer
}

// ---------------------------------------------------------------------------
// (256,2) ON PURPOSE: caps VGPR at 128. A/B-tested R8 vs R9: VGPR-128 +
// ~9 MB scratch spill runs 160 us; clean VGPR-160 runs 207 us (occupancy
// halves past the 128-VGPR wave-allocation step). Do not "fix" the spill.
__global__ __launch_bounds__(256, 2) void sage_fused(
    const float* __restrict__ node_feat,
    const int* __restrict__ cnt, const unsigned* __restrict__ pairs,
    const float* __restrict__ esh, int nsh,
    const _Float16* __restrict__ Wpack, const float* __restrict__ park,
    float* __restrict__ out) {

    __shared__ _Float16 Hs[128][264];   // +8-half pad
    __shared__ float es[128];
    __shared__ float wf[256];
    __shared__ float red[2][128];

    const int tid  = threadIdx.x;
    const int wave = tid >> 6;
    const int lane = tid & 63;
    const int m_   = lane & 15;
    const int quad = lane >> 4;
    const int node0 = blockIdx.x * 128;

    if (tid < 128) es[tid] = 0.f;
    __syncthreads();

    // ---- stage node_feat tile (fp32 -> fp16) ----
    for (int idx = tid; idx < 128 * 16; idx += 256) {
        const int row = idx >> 4, g = idx & 15;
        int node = node0 + row; if (node >= N_NODES) node = N_NODES - 1;
        const float4* src = (const float4*)(node_feat + (size_t)node * 128 + g * 8);
        const float4 v0 = src[0], v1 = src[1];
        half8 h;
        h[0] = (_Float16)v0.x; h[1] = (_Float16)v0.y;
        h[2] = (_Float16)v0.z; h[3] = (_Float16)v0.w;
        h[4] = (_Float16)v1.x; h[5] = (_Float16)v1.y;
        h[6] = (_Float16)v1.z; h[7] = (_Float16)v1.w;
        *(half8*)&Hs[row][g * 8] = h;
    }
    // ---- edge aggregate for this 128-node tile (1:1 bucket) ----
    if (nsh == 0) {
        const int c = min(cnt[blockIdx.x], CAP);
        const unsigned* __restrict__ pp = pairs + (size_t)blockIdx.x * CAP;
        for (int i = tid; i < c; i += 256) {
            const unsigned p = pp[i];
            atomicAdd(&es[p & 127u], __uint_as_float(p & 0xFFFFFF00u));
        }
    } else if (tid < 128) {
        int node = node0 + tid; if (node >= N_NODES) node = N_NODES - 1;
        float s = 0.f;
        for (int sh = 0; sh < nsh; ++sh) s += esh[(size_t)sh * SH_STRIDE + node];
        es[tid] = s;
    }
    __syncthreads();

    // layer 0: K=128; layers 1..6: K=256 (in-place Hs, 2 barriers each)
    layer_mm<128>(Wpack, Hs, es, park, wave, m_, quad);
    for (int l = 1; l < 7; ++l)
        layer_mm<256>(Wpack + 32768 + (l - 1) * 65536, Hs, es, park + l * 512,
                      wave, m_, quad);

    // ---- final 256 -> 1 dot (fp32) ----
    wf[tid] = park[3584 + tid];
    __syncthreads();
    {
        const int row = tid & 127, seg = tid >> 7;
        const _Float16* hp = &Hs[row][seg * 128];
        const float* wpt = &wf[seg * 128];
        float s = 0.f;
        #pragma unroll 8
        for (int k = 0; k < 128; ++k) s += (float)hp[k] * wpt[k];
        red[seg][row] = s;
    }
    __syncthreads();
    if (tid < 128) {
        const int node = node0 + tid;
        if (node < N_NODES)
            out[node] = red[0][tid] + red[1][tid] + park[3840];
    }
}

// ---------------------------------------------------------------------------
extern "C" void kernel_launch(void* const* d_in, const int* in_sizes, int n_in,
                              void* d_out, int out_size, void* d_ws,
                              size_t ws_size, hipStream_t stream) {
    const float* node_feat = (const float*)d_in[0];
    const float* edge_feat = (const float*)d_in[1];
    const int*   edge_dst  = (const int*)d_in[2];
    const float* W1  = (const float*)d_in[3];  const float* b1  = (const float*)d_in[4];
    const float* Wm1 = (const float*)d_in[5];  const float* bm1 = (const float*)d_in[6];
    const float* Wm2 = (const float*)d_in[7];  const float* bm2 = (const float*)d_in[8];
    const float* Wm3 = (const float*)d_in[9];  const float* bm3 = (const float*)d_in[10];
    const float* Wm4 = (const float*)d_in[11]; const float* bm4 = (const float*)d_in[12];
    const float* Wr1 = (const float*)d_in[13]; const float* br1 = (const float*)d_in[14];
    const float* Wr2 = (const float*)d_in[15]; const float* br2 = (const float*)d_in[16];
    const float* Wr3 = (const float*)d_in[17]; const float* br3 = (const float*)d_in[18];
    float* out = (float*)d_out;

    // ws layout: Wp | park | counts | cnt | pairs (fallback: esh over pairs)
    char* ws = (char*)d_ws;
    _Float16* Wp     = (_Float16*)ws;                      // 851968 B
    float*    park   = (float*)(ws + 851968);              // 16384 B
    int*      counts = (int*)(ws + 868352);                // NBIN*NBUCK*4 = 613088 B
    int*      cnt    = (int*)(ws + 1481440);               // 3128 B (pad to 1484800)
    unsigned* pairs  = (unsigned*)(ws + 1484800);          // NBUCK*CAP*4 = 16015360 B
    float*    esh    = (float*)(ws + 1484800);             // fallback shadows

    const size_t need_bins = 1484800 + (size_t)NBUCK * CAP * 4;   // ~17.5 MB
    const bool use_bins = (ws_size >= need_bins);

    const int nblk = (N_NODES + 127) / 128;   // 782

    if (use_bins) {
        hist_pack<<<NBIN + NPK, 1024, 0, stream>>>(
            edge_dst, W1, Wm1, Wm2, Wm3, Wm4, Wr1, Wr2,
            b1, bm1, bm2, bm3, bm4, br1, br2, Wr3, br3,
            counts, Wp, park, 1);
        scan_k<<<1, 1024, 0, stream>>>(counts, cnt);
        place_k<<<NBIN, 1024, 0, stream>>>(edge_feat, edge_dst, counts, pairs);
        sage_fused<<<nblk, 256, 0, stream>>>(node_feat, cnt, pairs,
                                             nullptr, 0, Wp, park, out);
    } else {
        hist_pack<<<NPK, 1024, 0, stream>>>(
            edge_dst, W1, Wm1, Wm2, Wm3, Wm4, Wr1, Wr2,
            b1, bm1, bm2, bm3, bm4, br1, br2, Wr3, br3,
            counts, Wp, park, 0);
        hipMemsetAsync(esh, 0, (size_t)4 * SH_STRIDE * 4, stream);
        scatter4<<<3125, 256, 0, stream>>>((const float4*)edge_feat,
                                           (const int4*)edge_dst, esh);
        sage_fused<<<nblk, 256, 0, stream>>>(node_feat, nullptr, nullptr,
                                             esh, 4, Wp, park, out);
    }
}

// Round 11
// 286.042 us; speedup vs baseline: 1.1564x; 1.1057x over previous
//
#include <hip/hip_runtime.h>
#include <hip/hip_bf16.h>

typedef _Float16 half8  __attribute__((ext_vector_type(8)));
typedef _Float16 half4v __attribute__((ext_vector_type(4)));
typedef float    f32x4  __attribute__((ext_vector_type(4)));

#define N_NODES 100000
#define N_EDGES 3200000
#define SH_STRIDE 100096   // fallback shadow stride (floats)
#define NBUCK 782          // 128 nodes per bucket == one sage tile
#define CAP   5120         // records/bucket: mean 4092 + 16 sigma
#define CHUNK 8192         // edges per bin block (1024 thr x 2 x int4)
#define NBIN  391          // ceil(N_EDGES/CHUNK)
#define NPK   16           // pack blocks appended to bin grid

// ---------------------------------------------------------------------------
// Merged bin + pack kernel, 1024-thread blocks, ~77 KB LDS -> 2 blocks/CU
// (the R9 counting sort was 111 KB -> 1 block/CU; halving CHUNK doubles the
// CU-level parallelism hiding the sort's LDS + scattered-store latency).
// bin blocks [0,NBIN): block-local counting sort for COALESCED output:
//   phase1: LDS histogram by dst>>7 (edges held in registers)
//   reserve: one global atomic per nonzero bucket (~306K total)
//   scan:    Hillis-Steele prefix over 1024 slots -> LDS group bases
//   phase2:  place {record, gslot} into LDS grouped by bucket
//   phase3:  linear LDS read -> runs of consecutive gslot -> coalesced stores
//   record = (fp32_bits & 0xFFFFFF00) | (dst & 127)   (rel err <= 2^-16)
// pack blocks [NBIN,NBIN+NPK): weights fp32->fp16 + park[] table:
//   park[l*512+j]=we_l[j]; park[l*512+256+j]=bias_l[j];
//   park[3584+j]=wr3[j]; park[3840]=br3[0]
// ---------------------------------------------------------------------------
__global__ __launch_bounds__(1024) void binpack(
    const float* __restrict__ ef, const int* __restrict__ dst,
    const float* __restrict__ W1,  const float* __restrict__ Wm1,
    const float* __restrict__ Wm2, const float* __restrict__ Wm3,
    const float* __restrict__ Wm4, const float* __restrict__ Wr1,
    const float* __restrict__ Wr2,
    const float* __restrict__ b1,  const float* __restrict__ bm1,
    const float* __restrict__ bm2, const float* __restrict__ bm3,
    const float* __restrict__ bm4, const float* __restrict__ br1,
    const float* __restrict__ br2, const float* __restrict__ wr3,
    const float* __restrict__ br3,
    int* __restrict__ cursor, unsigned* __restrict__ pairs,
    _Float16* __restrict__ Wp, float* __restrict__ park, int do_bin) {

    if (do_bin && blockIdx.x < NBIN) {
        __shared__ int      hist[NBUCK];
        __shared__ int      base[NBUCK];   // absolute global base per bucket
        __shared__ int      scan[1024];    // prefix-sum workspace
        __shared__ int      lbase[NBUCK];  // LDS group base per bucket
        __shared__ unsigned lrec[CHUNK];   // grouped records
        __shared__ int      lslot[CHUNK];  // grouped global slots (-1 = drop)
        const int start = blockIdx.x * CHUNK;
        const int tid   = threadIdx.x;
        for (int b = tid; b < NBUCK; b += 1024) hist[b] = 0;
        __syncthreads();

        int4   dreg[2];
        float4 freg[2];
        #pragma unroll
        for (int it = 0; it < 2; ++it) {
            const int i = start + (it * 1024 + tid) * 4;
            if (i < N_EDGES) {
                dreg[it] = *(const int4*)&dst[i];
                freg[it] = *(const float4*)&ef[i];
                atomicAdd(&hist[dreg[it].x >> 7], 1);
                atomicAdd(&hist[dreg[it].y >> 7], 1);
                atomicAdd(&hist[dreg[it].z >> 7], 1);
                atomicAdd(&hist[dreg[it].w >> 7], 1);
            }
        }
        __syncthreads();
        // reserve global space; seed scan with counts
        if (tid < NBUCK) {
            const int c = hist[tid];
            base[tid] = tid * CAP + ((c > 0) ? atomicAdd(&cursor[tid], c) : 0);
            scan[tid] = c;
        } else {
            scan[tid] = 0;
        }
        __syncthreads();
        // Hillis-Steele inclusive scan over 1024 slots
        #pragma unroll
        for (int ofs = 1; ofs < 1024; ofs <<= 1) {
            const int v = (tid >= ofs) ? scan[tid - ofs] : 0;
            __syncthreads();
            scan[tid] += v;
            __syncthreads();
        }
        if (tid < NBUCK) {
            lbase[tid] = scan[tid] - hist[tid];   // exclusive
            hist[tid]  = 0;                        // reuse as running rank
        }
        __syncthreads();
        // phase2: place into LDS grouped by bucket
        #pragma unroll
        for (int it = 0; it < 2; ++it) {
            const int i = start + (it * 1024 + tid) * 4;
            if (i < N_EDGES) {
                const int4   d = dreg[it];
                const float4 f = freg[it];
                {   const int bk = d.x >> 7; const int r = atomicAdd(&hist[bk], 1);
                    const int s = lbase[bk] + r; const int g = base[bk] + r;
                    lrec[s]  = (__float_as_uint(f.x) & 0xFFFFFF00u) | (unsigned)(d.x & 127);
                    lslot[s] = (g < (bk + 1) * CAP) ? g : -1; }
                {   const int bk = d.y >> 7; const int r = atomicAdd(&hist[bk], 1);
                    const int s = lbase[bk] + r; const int g = base[bk] + r;
                    lrec[s]  = (__float_as_uint(f.y) & 0xFFFFFF00u) | (unsigned)(d.y & 127);
                    lslot[s] = (g < (bk + 1) * CAP) ? g : -1; }
                {   const int bk = d.z >> 7; const int r = atomicAdd(&hist[bk], 1);
                    const int s = lbase[bk] + r; const int g = base[bk] + r;
                    lrec[s]  = (__float_as_uint(f.z) & 0xFFFFFF00u) | (unsigned)(d.z & 127);
                    lslot[s] = (g < (bk + 1) * CAP) ? g : -1; }
                {   const int bk = d.w >> 7; const int r = atomicAdd(&hist[bk], 1);
                    const int s = lbase[bk] + r; const int g = base[bk] + r;
                    lrec[s]  = (__float_as_uint(f.w) & 0xFFFFFF00u) | (unsigned)(d.w & 127);
                    lslot[s] = (g < (bk + 1) * CAP) ? g : -1; }
            }
        }
        __syncthreads();
        // phase3: coalesced run writes (consecutive s within a bucket run
        // -> consecutive global slots)
        const int total = min(CHUNK, N_EDGES - start);
        for (int s = tid; s < total; s += 1024) {
            const int g = lslot[s];
            if (g >= 0) pairs[g] = lrec[s];
        }
    } else {
        const float* srcs[7] = {W1, Wm1, Wm2, Wm3, Wm4, Wr1, Wr2};
        const float* bias[7] = {b1, bm1, bm2, bm3, bm4, br1, br2};
        const int pb  = do_bin ? ((int)blockIdx.x - NBIN) : (int)blockIdx.x;
        const int gid = pb * 1024 + threadIdx.x;
        const int gsz = NPK * 1024;
        for (int i = gid; i < 425984; i += gsz) {
            int job, row, k, stride;
            if (i < 32768) { job = 0; row = i >> 7; k = i & 127; stride = 129; }
            else {
                int t = i - 32768; job = 1 + (t >> 16); int w = t & 65535;
                row = w >> 8; k = w & 255; stride = (job == 6) ? 256 : 257;
            }
            Wp[i] = (_Float16)srcs[job][row * stride + k];
        }
        for (int i = gid; i < 1536; i += gsz) {
            const int job = i >> 8, row = i & 255;
            const int stride = (job == 0) ? 129 : 257;
            const int kin    = (job == 0) ? 128 : 256;
            park[job * 512 + row] = srcs[job][row * stride + kin];
        }
        for (int i = gid; i < 256; i += gsz) park[6 * 512 + i] = 0.f;
        for (int i = gid; i < 1792; i += gsz)
            park[(i >> 8) * 512 + 256 + (i & 255)] = bias[i >> 8][i & 255];
        for (int i = gid; i < 256; i += gsz) park[3584 + i] = wr3[i];
        if (gid == 0) park[3840] = br3[0];
    }
}

// fallback: device-scope split-4 scatter (known-good)
__global__ void scatter4(const float4* __restrict__ ef4,
                         const int4* __restrict__ dst4,
                         float* __restrict__ e) {
    const int n4 = N_EDGES / 4;
    for (int i = blockIdx.x * blockDim.x + threadIdx.x; i < n4;
         i += gridDim.x * blockDim.x) {
        const float4 f = ef4[i];
        const int4   d = dst4[i];
        atomicAdd(&e[d.x], f.x);
        atomicAdd(&e[SH_STRIDE + d.y], f.y);
        atomicAdd(&e[2 * SH_STRIDE + d.z], f.z);
        atomicAdd(&e[3 * SH_STRIDE + d.w], f.w);
    }
}

// ---------------------------------------------------------------------------
// One layer over a 128-node tile (R8-proven config). Wave owns 64 output cols
// x 128 nodes: jt4 x mt8. a-frag = W rows from global/L2, prefetched one
// k-step ahead; b-frag = H rows via ds_read_b128. Epilogue constants from
// park in registers. Two barriers per layer.
// ---------------------------------------------------------------------------
template<int K>
__device__ __forceinline__ void layer_mm(const _Float16* __restrict__ Wl,
                                         _Float16 (* __restrict__ Hs)[264],
                                         const float* __restrict__ es,
                                         const float* __restrict__ parkl,
                                         int wave, int m_, int quad) {
    f32x4 acc[4][8];
    #pragma unroll
    for (int jt = 0; jt < 4; ++jt)
        #pragma unroll
        for (int mt = 0; mt < 8; ++mt)
            acc[jt][mt] = (f32x4){0.f, 0.f, 0.f, 0.f};

    const int jb0 = wave * 64 + quad * 4;
    float4 w4[4], bb[4];
    #pragma unroll
    for (int jt = 0; jt < 4; ++jt) {
        w4[jt] = *(const float4*)&parkl[jt * 16 + jb0];
        bb[jt] = *(const float4*)&parkl[256 + jt * 16 + jb0];
    }

    const _Float16* __restrict__ wp = Wl + (size_t)(wave * 64 + m_) * K + quad * 8;

    half8 a[4];
    #pragma unroll
    for (int jt = 0; jt < 4; ++jt)
        a[jt] = *(const half8*)(wp + jt * 16 * K);

    #pragma unroll
    for (int kk = 0; kk < K; kk += 32) {
        half8 a2[4];
        if (kk + 32 < K) {
            #pragma unroll
            for (int jt = 0; jt < 4; ++jt)
                a2[jt] = *(const half8*)(wp + jt * 16 * K + kk + 32);
        }
        half8 b[8];
        #pragma unroll
        for (int mt = 0; mt < 8; ++mt)
            b[mt] = *(const half8*)&Hs[mt * 16 + m_][kk + quad * 8];
        #pragma unroll
        for (int jt = 0; jt < 4; ++jt)
            #pragma unroll
            for (int mt = 0; mt < 8; ++mt)
                acc[jt][mt] = __builtin_amdgcn_mfma_f32_16x16x32_f16(
                    a[jt], b[mt], acc[jt][mt], 0, 0, 0);
        if (kk + 32 < K) {
            #pragma unroll
            for (int jt = 0; jt < 4; ++jt) a[jt] = a2[jt];
        }
    }
    __syncthreads();   // all waves done reading Hs

    #pragma unroll
    for (int jt = 0; jt < 4; ++jt) {
        const int jbase = jb0 + jt * 16;
        #pragma unroll
        for (int mt = 0; mt < 8; ++mt) {
            const int node = mt * 16 + m_;
            const float ev = es[node];
            half4v h;
            h[0] = (_Float16)fmaxf(acc[jt][mt][0] + ev * w4[jt].x + bb[jt].x, 0.f);
            h[1] = (_Float16)fmaxf(acc[jt][mt][1] + ev * w4[jt].y + bb[jt].y, 0.f);
            h[2] = (_Float16)fmaxf(acc[jt][mt][2] + ev * w4[jt].z + bb[jt].z, 0.f);
            h[3] = (_Float16)fmaxf(acc[jt][mt][3] + ev * w4[jt].w + bb[jt].w, 0.f);
            *(half4v*)&Hs[node][jbase] = h;
        }
    }
    __syncthreads();   // Hs writes visible before next layer
}

// ---------------------------------------------------------------------------
// (256,2) ON PURPOSE: caps VGPR at 128. A/B-tested R8 vs R9: VGPR-128 +
// ~9 MB cold scratch spill runs 160-172 us; clean VGPR-160 runs 203-207 us
// (occupancy halves past the 128-VGPR wave-allocation step). Do not "fix"
// the spill.
__global__ __launch_bounds__(256, 2) void sage_fused(
    const float* __restrict__ node_feat,
    const int* __restrict__ cursor, const unsigned* __restrict__ pairs,
    const float* __restrict__ esh, int nsh,
    const _Float16* __restrict__ Wpack, const float* __restrict__ park,
    float* __restrict__ out) {

    __shared__ _Float16 Hs[128][264];   // +8-half pad
    __shared__ float es[128];
    __shared__ float wf[256];
    __shared__ float red[2][128];

    const int tid  = threadIdx.x;
    const int wave = tid >> 6;
    const int lane = tid & 63;
    const int m_   = lane & 15;
    const int quad = lane >> 4;
    const int node0 = blockIdx.x * 128;

    if (tid < 128) es[tid] = 0.f;
    __syncthreads();

    // ---- stage node_feat tile (fp32 -> fp16) ----
    for (int idx = tid; idx < 128 * 16; idx += 256) {
        const int row = idx >> 4, g = idx & 15;
        int node = node0 + row; if (node >= N_NODES) node = N_NODES - 1;
        const float4* src = (const float4*)(node_feat + (size_t)node * 128 + g * 8);
        const float4 v0 = src[0], v1 = src[1];
        half8 h;
        h[0] = (_Float16)v0.x; h[1] = (_Float16)v0.y;
        h[2] = (_Float16)v0.z; h[3] = (_Float16)v0.w;
        h[4] = (_Float16)v1.x; h[5] = (_Float16)v1.y;
        h[6] = (_Float16)v1.z; h[7] = (_Float16)v1.w;
        *(half8*)&Hs[row][g * 8] = h;
    }
    // ---- edge aggregate for this 128-node tile (1:1 bucket) ----
    if (nsh == 0) {
        const int cnt = min(cursor[blockIdx.x], CAP);
        const unsigned* __restrict__ pp = pairs + (size_t)blockIdx.x * CAP;
        for (int i = tid; i < cnt; i += 256) {
            const unsigned p = pp[i];
            atomicAdd(&es[p & 127u], __uint_as_float(p & 0xFFFFFF00u));
        }
    } else if (tid < 128) {
        int node = node0 + tid; if (node >= N_NODES) node = N_NODES - 1;
        float s = 0.f;
        for (int sh = 0; sh < nsh; ++sh) s += esh[(size_t)sh * SH_STRIDE + node];
        es[tid] = s;
    }
    __syncthreads();

    // layer 0: K=128; layers 1..6: K=256 (in-place Hs, 2 barriers each)
    layer_mm<128>(Wpack, Hs, es, park, wave, m_, quad);
    for (int l = 1; l < 7; ++l)
        layer_mm<256>(Wpack + 32768 + (l - 1) * 65536, Hs, es, park + l * 512,
                      wave, m_, quad);

    // ---- final 256 -> 1 dot (fp32) ----
    wf[tid] = park[3584 + tid];
    __syncthreads();
    {
        const int row = tid & 127, seg = tid >> 7;
        const _Float16* hp = &Hs[row][seg * 128];
        const float* wpt = &wf[seg * 128];
        float s = 0.f;
        #pragma unroll 8
        for (int k = 0; k < 128; ++k) s += (float)hp[k] * wpt[k];
        red[seg][row] = s;
    }
    __syncthreads();
    if (tid < 128) {
        const int node = node0 + tid;
        if (node < N_NODES)
            out[node] = red[0][tid] + red[1][tid] + park[3840];
    }
}

// ---------------------------------------------------------------------------
extern "C" void kernel_launch(void* const* d_in, const int* in_sizes, int n_in,
                              void* d_out, int out_size, void* d_ws,
                              size_t ws_size, hipStream_t stream) {
    const float* node_feat = (const float*)d_in[0];
    const float* edge_feat = (const float*)d_in[1];
    const int*   edge_dst  = (const int*)d_in[2];
    const float* W1  = (const float*)d_in[3];  const float* b1  = (const float*)d_in[4];
    const float* Wm1 = (const float*)d_in[5];  const float* bm1 = (const float*)d_in[6];
    const float* Wm2 = (const float*)d_in[7];  const float* bm2 = (const float*)d_in[8];
    const float* Wm3 = (const float*)d_in[9];  const float* bm3 = (const float*)d_in[10];
    const float* Wm4 = (const float*)d_in[11]; const float* bm4 = (const float*)d_in[12];
    const float* Wr1 = (const float*)d_in[13]; const float* br1 = (const float*)d_in[14];
    const float* Wr2 = (const float*)d_in[15]; const float* br2 = (const float*)d_in[16];
    const float* Wr3 = (const float*)d_in[17]; const float* br3 = (const float*)d_in[18];
    float* out = (float*)d_out;

    // ws layout: cursor | Wp | park | pairs (fallback: esh over pairs)
    char* ws = (char*)d_ws;
    int*      cursor = (int*)ws;                           // 4096 B reserved
    _Float16* Wp     = (_Float16*)(ws + 4096);             // 851968 B
    float*    park   = (float*)(ws + 856064);              // 16384 B
    unsigned* pairs  = (unsigned*)(ws + 872448);           // NBUCK*CAP*4 B
    float*    esh    = (float*)(ws + 872448);              // fallback shadows

    const size_t need_bins = 872448 + (size_t)NBUCK * CAP * 4;   // ~16.9 MB
    const bool use_bins = (ws_size >= need_bins);

    const int nblk = (N_NODES + 127) / 128;   // 782

    if (use_bins) {
        hipMemsetAsync(cursor, 0, NBUCK * sizeof(int), stream);
        binpack<<<NBIN + NPK, 1024, 0, stream>>>(
            edge_feat, edge_dst, W1, Wm1, Wm2, Wm3, Wm4, Wr1, Wr2,
            b1, bm1, bm2, bm3, bm4, br1, br2, Wr3, br3,
            cursor, pairs, Wp, park, 1);
        sage_fused<<<nblk, 256, 0, stream>>>(node_feat, cursor, pairs,
                                             nullptr, 0, Wp, park, out);
    } else {
        binpack<<<NPK, 1024, 0, stream>>>(
            edge_feat, edge_dst, W1, Wm1, Wm2, Wm3, Wm4, Wr1, Wr2,
            b1, bm1, bm2, bm3, bm4, br1, br2, Wr3, br3,
            cursor, pairs, Wp, park, 0);
        hipMemsetAsync(esh, 0, (size_t)4 * SH_STRIDE * 4, stream);
        scatter4<<<3125, 256, 0, stream>>>((const float4*)edge_feat,
                                           (const int4*)edge_dst, esh);
        sage_fused<<<nblk, 256, 0, stream>>>(node_feat, nullptr, nullptr,
                                             esh, 4, Wp, park, out);
    }
}